// Round 8
// baseline (68.586 us; speedup 1.0000x reference)
//
#include <hip/hip_runtime.h>
#include <hip/hip_bf16.h>
#include <stdint.h>

#define N_ATOMS 131072
#define D_IN    128
#define D_HID   256
#define N_ELEM  4
#define NPAD    (N_ATOMS + N_ELEM * 64)   // 131328 slots max
#define K4_BLOCKS 512                      // 2/CU, expert = blockIdx&3
#define HIST_BLOCKS 128                    // 128 x 1024 atoms

typedef __attribute__((ext_vector_type(8))) short bf16x8;
typedef __attribute__((ext_vector_type(4))) float f32x4;

// ws layout (bytes):
//   [0,       262144): W1t bf16 [4][256][128] (h-major, k contiguous, LINEAR)
//   [262144,  262160): counts[4]
//   [262176,  262200): startArr[5]
//   [262272,  270464): bpart4[512*4] float (per-wave partials)
//   [270592,  272640): blockCounts[128][4] int
//   [278784,  280832): blockOff[128][4] int
//   [287232,  812544): sortedIdx[NPAD] int
#define WS_COUNTS 262144
#define WS_START  262176
#define WS_BPART  262272
#define WS_BCNT   270592
#define WS_BOFF   278784
#define WS_SIDX   287232

__device__ __forceinline__ unsigned short f2bf_rne(float f) {
    union { float f; unsigned u; } v; v.f = f;
    unsigned r = v.u + 0x7FFFu + ((v.u >> 16) & 1u);   // RNE
    return (unsigned short)(r >> 16);
}

// K1 (fused): blocks 0..31 transpose W1 -> W1t bf16; blocks 32..159 histogram.
__global__ void tnn_k1_fused(const int* __restrict__ eid, int* __restrict__ bcnt,
                             const float* __restrict__ W1, unsigned short* __restrict__ W1t) {
    __shared__ float tile[64][65];
    __shared__ int lc[N_ELEM];
    int t = threadIdx.x;
    if (blockIdx.x < 32) {
        int b  = blockIdx.x;
        int e  = b >> 3;
        int k0 = ((b >> 2) & 1) * 64;
        int h0 = (b & 3) * 64;
        int cg = t & 15;
        int rr = t >> 4;
        const float* src = W1 + ((size_t)e * D_IN + k0) * D_HID + h0;
        #pragma unroll
        for (int j = 0; j < 4; ++j) {
            int row = rr + j * 16;
            f32x4 v = *(const f32x4*)(src + (size_t)row * D_HID + cg * 4);
            tile[row][cg * 4 + 0] = v[0];
            tile[row][cg * 4 + 1] = v[1];
            tile[row][cg * 4 + 2] = v[2];
            tile[row][cg * 4 + 3] = v[3];
        }
        __syncthreads();
        unsigned short* dst = W1t + ((size_t)e * D_HID + h0) * D_IN + k0;
        #pragma unroll
        for (int j = 0; j < 4; ++j) {
            int hrow = rr + j * 16;
            ushort4 o;
            o.x = f2bf_rne(tile[cg * 4 + 0][hrow]);
            o.y = f2bf_rne(tile[cg * 4 + 1][hrow]);
            o.z = f2bf_rne(tile[cg * 4 + 2][hrow]);
            o.w = f2bf_rne(tile[cg * 4 + 3][hrow]);
            *(ushort4*)(dst + (size_t)hrow * D_IN + cg * 4) = o;
        }
    } else {
        int hb = blockIdx.x - 32;
        if (t < N_ELEM) lc[t] = 0;
        __syncthreads();
        int base = hb * 1024;
        #pragma unroll
        for (int r = 0; r < 4; ++r)
            atomicAdd(&lc[eid[base + r * 256 + t]], 1);
        __syncthreads();
        if (t < N_ELEM) bcnt[hb * 4 + t] = lc[t];
    }
}

// K2: one wave, shfl scan of 128 int4 block counts -> counts/starts/blockOff.
__global__ void tnn_k2_scan(const int* __restrict__ bcnt, int* __restrict__ counts,
                            int* __restrict__ startArr, int* __restrict__ boff) {
    int t = threadIdx.x;     // 0..63
    int4 c0 = ((const int4*)bcnt)[2 * t];
    int4 c1 = ((const int4*)bcnt)[2 * t + 1];
    int4 s  = {c0.x + c1.x, c0.y + c1.y, c0.z + c1.z, c0.w + c1.w};
    int4 incl = s;
    #pragma unroll
    for (int off = 1; off < 64; off <<= 1) {
        int ux = __shfl_up(incl.x, off);
        int uy = __shfl_up(incl.y, off);
        int uz = __shfl_up(incl.z, off);
        int uw = __shfl_up(incl.w, off);
        if (t >= off) { incl.x += ux; incl.y += uy; incl.z += uz; incl.w += uw; }
    }
    int4 tot = {__shfl(incl.x, 63), __shfl(incl.y, 63), __shfl(incl.z, 63), __shfl(incl.w, 63)};
    int st0 = 0;
    int st1 = st0 + ((tot.x + 63) & ~63);
    int st2 = st1 + ((tot.y + 63) & ~63);
    int st3 = st2 + ((tot.z + 63) & ~63);
    int st4 = st3 + ((tot.w + 63) & ~63);
    int4 run = {incl.x - s.x, incl.y - s.y, incl.z - s.z, incl.w - s.w};  // exclusive
    int4 o0 = {st0 + run.x, st1 + run.y, st2 + run.z, st3 + run.w};
    ((int4*)boff)[2 * t] = o0;
    run.x += c0.x; run.y += c0.y; run.z += c0.z; run.w += c0.w;
    int4 o1 = {st0 + run.x, st1 + run.y, st2 + run.z, st3 + run.w};
    ((int4*)boff)[2 * t + 1] = o1;
    if (t == 0) {
        ((int4*)counts)[0] = tot;
        startArr[0] = st0; startArr[1] = st1; startArr[2] = st2;
        startArr[3] = st3; startArr[4] = st4;
    }
}

// K3: scatter with per-block bases (LDS rank atomics only).
__global__ void tnn_k3_scatter(const int* __restrict__ eid, const int* __restrict__ boff,
                               int* __restrict__ sortedIdx) {
    __shared__ int lc[N_ELEM];
    int t = threadIdx.x;
    if (t < N_ELEM) lc[t] = 0;
    __syncthreads();
    int base = blockIdx.x * 1024;
    #pragma unroll
    for (int r = 0; r < 4; ++r) {
        int i = base + r * 256 + t;
        int e = eid[i];
        int rank = atomicAdd(&lc[e], 1);
        sortedIdx[boff[blockIdx.x * 4 + e] + rank] = i;
    }
}

// K4: block stages its expert's FULL W1t (64 KB bf16, XOR-swizzled) into LDS
// once; each wave = one 64-atom tile x 256 hidden. A in regs (depth-2 gather
// pipeline), B via short-latency ds_read ping-pong. 2 blocks/CU.
__global__ __launch_bounds__(256, 2) void tnn_k4_mlp(
        const float* __restrict__ X, const int* __restrict__ sortedIdx,
        const int* __restrict__ startArr, const int* __restrict__ counts,
        const unsigned short* __restrict__ W1t, const float* __restrict__ b1,
        const float* __restrict__ W2, float* __restrict__ bpart4) {
    __shared__ unsigned char ldsB[65536];   // [256 h-rows][256 B], 16B-block swizzled
    const float C2 = 2.8853900817779268f;   // 2*log2(e)

    int t = threadIdx.x;
    int wid  = t >> 6;
    int lane = t & 63;
    int l15  = lane & 15;
    int lk   = lane >> 4;

    int e      = blockIdx.x & 3;
    int q      = blockIdx.x >> 2;            // 0..127
    int bstart = startArr[e];
    int cnt    = counts[e];
    int rend   = bstart + cnt;
    int Te     = (startArr[e + 1] - bstart) >> 6;
    int fb     = sortedIdx[bstart];          // always-valid fallback row

    // ---- stage B: thread t = expert h-row t; swizzle 16B block j ^= (row&7) ----
    {
        const unsigned short* src = W1t + (size_t)e * D_HID * D_IN + (size_t)t * D_IN;
        unsigned char* dst = ldsB + t * 256;
        unsigned swz = (unsigned)(t & 7) << 4;
        #pragma unroll
        for (int j = 0; j < 16; ++j) {
            bf16x8 v = *(const bf16x8*)(src + j * 8);
            *(bf16x8*)(dst + (((unsigned)j << 4) ^ swz)) = v;
        }
    }

    // preload b1/w2 (static-indexed, 32 regs)
    float b1v[16], w2v[16];
    #pragma unroll
    for (int nt = 0; nt < 16; ++nt) {
        b1v[nt] = b1[e * D_HID + nt * 16 + l15];
        w2v[nt] = W2[e * D_HID + nt * 16 + l15];
    }

    // per-lane swizzled LDS offsets for the 4 k-slice fragments (nt=0 row base)
    unsigned ldso[4];
    #pragma unroll
    for (int ks = 0; ks < 4; ++ks)
        ldso[ks] = (unsigned)l15 * 256u + ((((unsigned)(ks * 4 + lk)) << 4) ^ (((unsigned)(l15 & 7)) << 4));

    __syncthreads();   // B staged

    float partial = 0.f;
    for (int tt = q * 4 + wid; tt < Te; tt += 512) {
        int tb = bstart + tt * 64;
        bool full = (tb + 64 <= rend);

        int rows[4];
        #pragma unroll
        for (int m = 0; m < 4; ++m) {
            int slot = tb + m * 16 + l15;
            rows[m] = (slot < rend) ? sortedIdx[slot] : fb;
        }

        // ---- A gather: depth-2 load/convert pipeline ----
        bf16x8 a[4][4];
        f32x4 va[8], vb[8];
        auto loadrow = [&](int m, f32x4* v) {
            const float* xr = X + (size_t)rows[m] * D_IN + lk * 8;
            #pragma unroll
            for (int ks = 0; ks < 4; ++ks) {
                v[2 * ks]     = *(const f32x4*)(xr + ks * 32);
                v[2 * ks + 1] = *(const f32x4*)(xr + ks * 32 + 4);
            }
        };
        auto conv = [&](const f32x4* v, bf16x8* dst) {
            #pragma unroll
            for (int ks = 0; ks < 4; ++ks) {
                f32x4 v0 = v[2 * ks], v1 = v[2 * ks + 1];
                bf16x8 tv;
                tv[0] = (short)(__float_as_uint(v0[0]) >> 16);
                tv[1] = (short)(__float_as_uint(v0[1]) >> 16);
                tv[2] = (short)(__float_as_uint(v0[2]) >> 16);
                tv[3] = (short)(__float_as_uint(v0[3]) >> 16);
                tv[4] = (short)(__float_as_uint(v1[0]) >> 16);
                tv[5] = (short)(__float_as_uint(v1[1]) >> 16);
                tv[6] = (short)(__float_as_uint(v1[2]) >> 16);
                tv[7] = (short)(__float_as_uint(v1[3]) >> 16);
                dst[ks] = tv;
            }
        };
        loadrow(0, va);
        loadrow(1, vb);
        conv(va, a[0]);
        loadrow(2, va);
        conv(vb, a[1]);
        loadrow(3, vb);
        conv(va, a[2]);
        conv(vb, a[3]);

        float fnval = 16.f;
        if (!full) {
            int nv = 0;
            #pragma unroll
            for (int m = 0; m < 4; ++m)
                #pragma unroll
                for (int r = 0; r < 4; ++r)
                    nv += (tb + m * 16 + lk * 4 + r < rend) ? 1 : 0;
            fnval = (float)nv;
        }

        // ---- nt loop: ds_read ping-pong + 16 MFMA + epilogue ----
        bf16x8 cur[4], nxt[4];
        #pragma unroll
        for (int ks = 0; ks < 4; ++ks)
            cur[ks] = *(const bf16x8*)(ldsB + ldso[ks]);

        #pragma unroll
        for (int nt = 0; nt < 16; ++nt) {
            if (nt < 15) {
                #pragma unroll
                for (int ks = 0; ks < 4; ++ks)
                    nxt[ks] = *(const bf16x8*)(ldsB + ldso[ks] + (nt + 1) * 4096);
            }

            f32x4 acc[4];
            #pragma unroll
            for (int m = 0; m < 4; ++m) {
                acc[m] = f32x4{0.f, 0.f, 0.f, 0.f};
                #pragma unroll
                for (int ks = 0; ks < 4; ++ks)
                    acc[m] = __builtin_amdgcn_mfma_f32_16x16x32_bf16(a[m][ks], cur[ks], acc[m], 0, 0, 0);
            }

            // tanh(p) = 1 - 2/(exp2(C2*p)+1); sum w2*tanh = w2*(nval - 2*sum(rcp))
            float b1s = b1v[nt] * C2;
            float rsum = 0.f;
            #pragma unroll
            for (int m = 0; m < 4; ++m) {
                #pragma unroll
                for (int r = 0; r < 4; ++r) {
                    float exv = __builtin_amdgcn_exp2f(fmaf(C2, acc[m][r], b1s));
                    float rc  = __builtin_amdgcn_rcpf(exv + 1.f);
                    if (!full)
                        rc = (tb + m * 16 + lk * 4 + r < rend) ? rc : 0.f;
                    rsum += rc;
                }
            }
            partial = fmaf(w2v[nt], fmaf(-2.f, rsum, fnval), partial);

            if (nt < 15) {
                #pragma unroll
                for (int ks = 0; ks < 4; ++ks) cur[ks] = nxt[ks];
            }
        }
    }

    #pragma unroll
    for (int off = 32; off; off >>= 1)
        partial += __shfl_down(partial, off);
    if (lane == 0) bpart4[blockIdx.x * 4 + wid] = partial;   // plain store, per wave
}

// K5: single block reduces 2048 per-wave partials + analytic bias term.
__global__ void tnn_k5_reduce(const float* __restrict__ bpart4, const int* __restrict__ counts,
                              const float* __restrict__ b2, float* __restrict__ out) {
    __shared__ float r[4];
    int t = threadIdx.x;
    float s = 0.f;
    #pragma unroll
    for (int j = 0; j < 8; ++j) s += bpart4[j * 256 + t];
    #pragma unroll
    for (int off = 32; off; off >>= 1)
        s += __shfl_down(s, off);
    if ((t & 63) == 0) r[t >> 6] = s;
    __syncthreads();
    if (t == 0) {
        float acc = r[0] + r[1] + r[2] + r[3];
        #pragma unroll
        for (int e = 0; e < N_ELEM; ++e)
            acc += (float)counts[e] * b2[e];   // b2 is [E,1]
        out[0] = acc;
    }
}

extern "C" void kernel_launch(void* const* d_in, const int* in_sizes, int n_in,
                              void* d_out, int out_size, void* d_ws, size_t ws_size,
                              hipStream_t stream) {
    const float* X   = (const float*)d_in[0];
    const int*   eid = (const int*)  d_in[1];
    const float* W1  = (const float*)d_in[2];
    const float* b1  = (const float*)d_in[3];
    const float* W2  = (const float*)d_in[4];
    const float* b2  = (const float*)d_in[5];
    float* out = (float*)d_out;

    char* ws = (char*)d_ws;
    unsigned short* W1t = (unsigned short*)ws;
    int*   counts    = (int*)  (ws + WS_COUNTS);
    int*   startArr  = (int*)  (ws + WS_START);
    float* bpart4    = (float*)(ws + WS_BPART);
    int*   bcnt      = (int*)  (ws + WS_BCNT);
    int*   boff      = (int*)  (ws + WS_BOFF);
    int*   sortedIdx = (int*)  (ws + WS_SIDX);

    hipLaunchKernelGGL(tnn_k1_fused,   dim3(32 + HIST_BLOCKS), dim3(256), 0, stream, eid, bcnt, W1, W1t);
    hipLaunchKernelGGL(tnn_k2_scan,    dim3(1),                dim3(64),  0, stream, bcnt, counts, startArr, boff);
    hipLaunchKernelGGL(tnn_k3_scatter, dim3(HIST_BLOCKS),      dim3(256), 0, stream, eid, boff, sortedIdx);
    hipLaunchKernelGGL(tnn_k4_mlp,     dim3(K4_BLOCKS),        dim3(256), 0, stream,
                       X, sortedIdx, startArr, counts, W1t, b1, W2, bpart4);
    hipLaunchKernelGGL(tnn_k5_reduce,  dim3(1),                dim3(256), 0, stream, bpart4, counts, b2, out);
}